// Round 6
// baseline (243.733 us; speedup 1.0000x reference)
//
#include <hip/hip_runtime.h>

typedef unsigned long long u64;
typedef unsigned int u32;

static constexpr int NF = 17;      // features per point
static constexpr int BCOL = 9;     // beta column
static constexpr int CCOL = 14;    // first ccoord column (17-3)
static constexpr int CONDCAP = 1024;
static constexpr int RPB = 512;    // rows per block in k_filter
static constexpr int FT = 1024;    // k_finish threads
static constexpr int KB = 8;       // kill-pass batch depth (MLP)

#define T_B_F ((float)0.2)         // matches numpy float32(0.2)
#define R2_F  ((float)(0.7*0.7))   // matches numpy float32 semantics

__device__ __forceinline__ u64 kmax(u64 a, u64 b){ return a > b ? a : b; }

__device__ __forceinline__ u64 shfl_down_u64(u64 v, int off){
    u32 lo = (u32)v, hi = (u32)(v >> 32);
    lo = __shfl_down(lo, off, 64);
    hi = __shfl_down(hi, off, 64);
    return ((u64)hi << 32) | lo;
}

__device__ __forceinline__ u64 shfl_u64(u64 v, int lane){
    u32 lo = (u32)v, hi = (u32)(v >> 32);
    lo = __shfl(lo, lane, 64);
    hi = __shfl(hi, lane, 64);
    return ((u64)hi << 32) | lo;
}

__device__ __forceinline__ u64 shfl_xor_u64(u64 v, int mask){
    u32 lo = (u32)v, hi = (u32)(v >> 32);
    lo = __shfl_xor(lo, mask, 64);
    hi = __shfl_xor(hi, mask, 64);
    return ((u64)hi << 32) | lo;
}

__device__ __forceinline__ u64 waveReduceMax(u64 k){
    #pragma unroll
    for (int off = 32; off > 0; off >>= 1){
        u64 o = shfl_down_u64(k, off);
        if (o > k) k = o;
    }
    return k;
}

// distance with NO fp contraction — must match numpy (mul,mul,mul,add,add)
__device__ __forceinline__ float dist2(float cx, float cy, float cz,
                                       float rx, float ry, float rz){
    #pragma clang fp contract(off)
    float dx = cx - rx, dy = cy - ry, dz = cz - rz;
    float sx = dx * dx, sy = dy * dy, sz = dz * dz;
    return (sx + sy) + sz;
}

__device__ __forceinline__ u64 makeKey(float beta, u32 idx){
    return ((u64)__float_as_uint(beta) << 32) | (u64)(0xFFFFFFFFu - idx);
}

// ---------------- kernel 0: zero control block (4 KB) ----------------
__global__ void k_init(u32* ws){
    int t = threadIdx.x;
    if (t < 1024) ws[t] = 0;   // argmax[E], cnt[E], ncond[E], done
}

// ---------------- kernel 1: zero dout + filter beta>=T_B + per-event argmax ----
__global__ __launch_bounds__(512) void k_filter(
    const float4* __restrict__ x4, float4* __restrict__ out4,
    u64* __restrict__ argmax0, int* __restrict__ cnt0,
    float4* __restrict__ cA, int* __restrict__ iA,
    int P, int chunksPerEvent)
{
    __shared__ float lds[RPB * NF];           // 34816 B
    __shared__ int swc[8], swb[8], sbase;
    __shared__ u64 sred[8];

    int e = blockIdx.x / chunksPerEvent;
    int chunk = blockIdx.x % chunksPerEvent;
    int rowStart = chunk * RPB;
    size_t tile4 = (size_t)blockIdx.x * (RPB * NF / 4);   // 2176 float4 per tile

    float4* lds4 = (float4*)lds;
    const int N4 = RPB * NF / 4;
    float4 z = make_float4(0.f, 0.f, 0.f, 0.f);
    for (int i = threadIdx.x; i < N4; i += 512){
        lds4[i] = x4[tile4 + i];
        out4[tile4 + i] = z;                   // fused zero of dout
    }
    __syncthreads();

    int tid = threadIdx.x, lid = tid & 63, wid = tid >> 6;
    float be = lds[tid*NF+BCOL];
    float cx = lds[tid*NF+CCOL], cy = lds[tid*NF+CCOL+1], cz = lds[tid*NF+CCOL+2];
    bool kp = (be >= T_B_F);
    u64 bal = __ballot(kp);
    int wcnt = __popcll(bal);
    u64 lk = kp ? makeKey(be, (u32)(rowStart + tid)) : 0;
    u64 kw = waveReduceMax(lk);
    if (lid == 0){ swc[wid] = wcnt; sred[wid] = kw; }
    __syncthreads();
    if (tid == 0){
        int tot = 0;
        for (int w = 0; w < 8; w++){ swb[w] = tot; tot += swc[w]; }
        sbase = tot ? atomicAdd(&cnt0[e], tot) : 0;      // 1 returning atomic / block
        u64 m = sred[0];
        for (int i = 1; i < 8; i++) m = kmax(m, sred[i]);
        if (m) atomicMax(&argmax0[e], m);                // fire-and-forget
    }
    __syncthreads();
    if (kp){
        int pos = sbase + swb[wid] + __popcll(bal & ((1ull << lid) - 1));
        size_t eoff = (size_t)e * P;
        cA[eoff + pos] = make_float4(cx, cy, cz, be);
        iA[eoff + pos] = rowStart + tid;
    }
}

// ---------------- kernel 2: per-event NMS, multi-accept per pass.
// Invariant: a point is a condensate iff it is > r from every higher-key
// condensate (greedy MIS in key order); asso is never output, so only the
// condensate set matters. Per round:
//  (a) kill+compact pass vs refs accepted last round (8-deep batched, MLP),
//      collecting per-wave top-4 survivors (key,pos) on the fly;
//  (b) wave 0 resolves ALL candidates with key > tau_max (tau_max = max over
//      waves of each wave's 4th-best key — completeness guarantee) via
//      in-register bitonic sort + greedy walk -> next round's refs.
__global__ __launch_bounds__(1024) void k_finish(
    const float* __restrict__ x,
    float4* cA, int* iA, float4* cB, int* iB,
    const u64* __restrict__ argmax0, const int* __restrict__ cnt0,
    int* __restrict__ ncond, int* __restrict__ done,
    float* __restrict__ out, int P, int E)
{
    __shared__ u64 wtopk[64];
    __shared__ int wtopp[64];
    __shared__ float refX[64], refY[64], refZ[64];
    __shared__ int condL[CONDCAP];
    __shared__ int scnt, snc, snr;

    int e = blockIdx.x;
    int tid = threadIdx.x, lid = tid & 63, wid = tid >> 6;
    int n = cnt0[e];
    u64 key0 = argmax0[e];
    float4* cIn = cA + (size_t)e * P; int* iIn = iA + (size_t)e * P;
    float4* cOut = cB + (size_t)e * P; int* iOut = iB + (size_t)e * P;

    if (tid == 0){
        snc = 0; scnt = 0; snr = 0;
        float b0 = __uint_as_float((u32)(key0 >> 32));
        if (n > 0 && b0 >= T_B_F){
            u32 refIdx = 0xFFFFFFFFu - (u32)key0;
            condL[0] = (int)refIdx; snc = 1; snr = 1;
            size_t rbase = ((size_t)e * P + refIdx) * NF;
            refX[0] = x[rbase + CCOL];
            refY[0] = x[rbase + CCOL + 1];
            refZ[0] = x[rbase + CCOL + 2];
        }
    }
    __syncthreads();

    while (snr > 0){
        int nr = snr;

        // ---- (a) kill + compact + per-wave top-4 collect ----
        u64 k4a=0,k4b=0,k4c=0,k4d=0; int p4a=0,p4b=0,p4c=0,p4d=0;
        for (int base = 0; base < n; base += FT * KB){
            float4 cc[KB]; int ixv[KB]; bool kp[KB]; u64 bal[KB];
            #pragma unroll
            for (int k = 0; k < KB; k++){
                int i = base + tid + k * FT;
                bool inb = i < n; int ii = inb ? i : 0;
                cc[k] = cIn[ii]; ixv[k] = iIn[ii];
                kp[k] = inb;
            }
            #pragma unroll
            for (int k = 0; k < KB; k++){
                if (kp[k]){
                    for (int r = 0; r < nr; r++){
                        if (dist2(cc[k].x, cc[k].y, cc[k].z,
                                  refX[r], refY[r], refZ[r]) <= R2_F){ kp[k] = false; break; }
                    }
                }
            }
            int wcnt = 0;
            #pragma unroll
            for (int k = 0; k < KB; k++){ bal[k] = __ballot(kp[k]); wcnt += __popcll(bal[k]); }
            int wb = 0;
            if (lid == 0) wb = wcnt ? atomicAdd(&scnt, wcnt) : 0;
            wb = __shfl(wb, 0, 64);
            u64 lm = (1ull << lid) - 1;
            #pragma unroll
            for (int k = 0; k < KB; k++){
                if (kp[k]){
                    int pos = wb + __popcll(bal[k] & lm);
                    cOut[pos] = cc[k]; iOut[pos] = ixv[k];
                    u64 kk = makeKey(cc[k].w, (u32)ixv[k]);
                    if (kk > k4d){                    // sorted-insert, static indices
                        if (kk > k4a){ k4d=k4c;p4d=p4c; k4c=k4b;p4c=p4b; k4b=k4a;p4b=p4a; k4a=kk;p4a=pos; }
                        else if (kk > k4b){ k4d=k4c;p4d=p4c; k4c=k4b;p4c=p4b; k4b=kk;p4b=pos; }
                        else if (kk > k4c){ k4d=k4c;p4d=p4c; k4c=kk;p4c=pos; }
                        else { k4d=kk; p4d=pos; }
                    }
                }
                wb += __popcll(bal[k]);
            }
        }
        // wave-merge per-lane top4 -> wave top4 (excl-walk)
        {
            u64 excl = ~0ull;
            #pragma unroll
            for (int j = 0; j < 4; j++){
                u64 lk = 0; int lp = 0;
                if (k4a < excl && k4a > lk){ lk = k4a; lp = p4a; }
                if (k4b < excl && k4b > lk){ lk = k4b; lp = p4b; }
                if (k4c < excl && k4c > lk){ lk = k4c; lp = p4c; }
                if (k4d < excl && k4d > lk){ lk = k4d; lp = p4d; }
                #pragma unroll
                for (int off = 32; off > 0; off >>= 1){
                    u64 ok = shfl_down_u64(lk, off);
                    int op = __shfl_down(lp, off, 64);
                    if (ok > lk){ lk = ok; lp = op; }
                }
                lk = shfl_u64(lk, 0); lp = __shfl(lp, 0, 64);
                if (lid == 0){ wtopk[wid*4 + j] = lk; wtopp[wid*4 + j] = lp; }
                excl = lk;
            }
        }
        __syncthreads();                       // scnt, wtop visible
        n = scnt;
        { float4* t = cIn; cIn = cOut; cOut = t; }
        { int* t = iIn; iIn = iOut; iOut = t; }
        if (n == 0) break;

        // ---- (b) resolve next refs (wave 0 only) ----
        if (wid == 0){
            u64 key = wtopk[lid]; int pos = wtopp[lid];
            u64 tt = (lid < 16) ? wtopk[lid*4 + 3] : 0;
            u64 tau = waveReduceMax(tt); tau = shfl_u64(tau, 0);
            float cx = 0.f, cy = 0.f, cz = 0.f;
            if (key){ float4 c = cIn[pos]; cx = c.x; cy = c.y; cz = c.z; }
            // bitonic sort desc by key across 64 lanes, carrying coords
            #pragma unroll
            for (int bs = 2; bs <= 64; bs <<= 1){
                #pragma unroll
                for (int bj = bs >> 1; bj > 0; bj >>= 1){
                    u64 ok = shfl_xor_u64(key, bj);
                    float ox = __shfl_xor(cx, bj, 64);
                    float oy = __shfl_xor(cy, bj, 64);
                    float oz = __shfl_xor(cz, bj, 64);
                    bool lower = (lid & bj) == 0;
                    bool segDesc = (lid & bs) == 0;
                    bool takeOther = segDesc ? (lower ? (ok > key) : (ok < key))
                                             : (lower ? (ok < key) : (ok > key));
                    if (takeOther){ key = ok; cx = ox; cy = oy; cz = oz; }
                }
            }
            int killed = (key == 0) ? 1 : 0;
            int nrr = 0;
            int sb = snc;
            for (int j = 0; j < 64; j++){
                u64 kj = shfl_u64(key, j);
                if (kj == 0 || kj <= tau) break;       // completeness boundary
                int kb = __shfl(killed, j, 64);
                if (!kb){
                    float xj = __shfl(cx, j, 64);
                    float yj = __shfl(cy, j, 64);
                    float zj = __shfl(cz, j, 64);
                    if (lid == 0){
                        refX[nrr] = xj; refY[nrr] = yj; refZ[nrr] = zj;
                        int s = sb + nrr;
                        if (s < CONDCAP) condL[s] = (int)(0xFFFFFFFFu - (u32)kj);
                    }
                    nrr++;
                    if (dist2(cx, cy, cz, xj, yj, zj) <= R2_F) killed = 1;
                }
            }
            if (lid == 0){ snr = nrr; snc = sb + nrr; scnt = 0; }
        }
        __syncthreads();                       // snr/refs/scnt visible
    }
    __syncthreads();

    // ---- epilogue: scatter condensate rows + row_splits (last block) ----
    int ncT = snc;
    int ncc = ncT > CONDCAP ? CONDCAP : ncT;
    for (int i = tid; i < ncc * NF; i += FT){
        int j = i / NF, f = i - j * NF;
        int row = condL[j];
        size_t base = ((size_t)e * P + row) * NF;
        out[base + f] = x[base + f];
    }
    if (tid == 0){
        ncond[e] = ncT;
        __threadfence();
        int r = atomicAdd(done, 1);
        if (r == E - 1){                    // last block writes row_splits
            size_t ob = (size_t)E * P * NF;
            int s = 0;
            out[ob] = 0.0f;
            for (int i = 0; i < E; i++){
                s += atomicAdd(&ncond[i], 0);   // device-scope read
                out[ob + i + 1] = (float)s;
            }
        }
    }
}

extern "C" void kernel_launch(void* const* d_in, const int* in_sizes, int n_in,
                              void* d_out, int out_size, void* d_ws, size_t ws_size,
                              hipStream_t stream) {
    const float* x = (const float*)d_in[0];
    int N = in_sizes[0] / NF;
    int E = in_sizes[1] - 1;
    int P = N / E;
    float* out = (float*)d_out;
    char* ws = (char*)d_ws;

    // ws layout (first 4 KB zeroed by k_init)
    u64* argmax = (u64*)ws;                         // [E]
    int* cnt    = (int*)(ws + 1024);                // [E]
    int* ncond  = (int*)(ws + 2048);                // [E]
    int* done   = (int*)(ws + 2560);                // [1]
    size_t listOff = 32768;
    size_t listElems = (size_t)E * P;
    float4* cA = (float4*)(ws + listOff);
    float4* cB = (float4*)(ws + listOff + listElems * 16);
    int* iA = (int*)(ws + listOff + listElems * 32);
    int* iB = (int*)(ws + listOff + listElems * 36);

    k_init<<<1, 1024, 0, stream>>>((u32*)ws);

    int chunksPerEvent = P / RPB;                   // 128
    k_filter<<<E * chunksPerEvent, 512, 0, stream>>>(
        (const float4*)x, (float4*)out, argmax, cnt, cA, iA, P, chunksPerEvent);

    k_finish<<<E, 1024, 0, stream>>>(
        x, cA, iA, cB, iB, argmax, cnt, ncond, done, out, P, E);
}